// Round 10
// baseline (1082.805 us; speedup 1.0000x reference)
//
#include <hip/hip_runtime.h>
#include <hip/hip_fp16.h>

#define ND 48       // feature dim (floats)
#define NH 6        // used uint4 chunks per row (48/8)
#define HS 8        // row stride in uint4 (128B-aligned rows)
#define KSTEPS 10
#define ALPHA 0.1f

#define NPB_SHIFT 9
#define NPB 512             // nodes per bin
#define MAXBINS 256         // supports N <= 131072
#define CHB 2048            // edges per block, merged bin kernel
#define BINCAP 10240        // pair capacity per bin (mean 8163, +23 sigma)
#define SBINCAP 10240

// pack (src, dstLocal) into 4B: dstLocal<<18 | src   (src < 2^18, dstLocal < 2^9)
#define PACK(s, dl) (((unsigned)(dl) << 18) | (unsigned)(s))
#define UNPACK_SRC(v) ((int)((v) & 0x3FFFFu))
#define UNPACK_LOC(v) ((int)((v) >> 18))

// ---- fp16 pack/unpack helpers ----
__device__ inline float2 unpack2(unsigned int u) {
    __half2 h;
    *reinterpret_cast<unsigned int*>(&h) = u;
    return __half22float2(h);
}
__device__ inline unsigned int pack2(float x, float y) {
    __half2 h = __floats2half2_rn(x, y);
    return *reinterpret_cast<unsigned int*>(&h);
}
__device__ inline void add8(float* a, uint4 v) {
    float2 t;
    t = unpack2(v.x); a[0] += t.x; a[1] += t.y;
    t = unpack2(v.y); a[2] += t.x; a[3] += t.y;
    t = unpack2(v.z); a[4] += t.x; a[5] += t.y;
    t = unpack2(v.w); a[6] += t.x; a[7] += t.y;
}

// ========== merged binning: dst-binned packed pairs + src-binned values ====
__global__ __launch_bounds__(256) void bin_kernel(
        const int* __restrict__ src, const int* __restrict__ dst, int E,
        unsigned* __restrict__ gpairs, int* __restrict__ bincnt,
        int* __restrict__ gsrc, int* __restrict__ sbincnt, int nbins) {
    __shared__ unsigned s_pair[CHB];   // 8 KB
    __shared__ int s_srcv[CHB];        // 8 KB
    __shared__ int hP[MAXBINS], eP[MAXBINS], rP[MAXBINS], gP[MAXBINS];
    __shared__ int hS[MAXBINS], eS[MAXBINS], rS[MAXBINS], gS[MAXBINS];

    int tid = threadIdx.x;
    int e0 = blockIdx.x * CHB;
    int cnt = E - e0; if (cnt > CHB) cnt = CHB;

    hP[tid] = 0; rP[tid] = 0; hS[tid] = 0; rS[tid] = 0;
    __syncthreads();

    // pass 1: dual histogram
    for (int t = tid; t < cnt; t += 256) {
        atomicAdd(&hP[dst[e0 + t] >> NPB_SHIFT], 1);
        atomicAdd(&hS[src[e0 + t] >> NPB_SHIFT], 1);
    }
    __syncthreads();

    // dual exclusive scan over 256 bins
    int vP = hP[tid], vS = hS[tid];
    eP[tid] = vP; eS[tid] = vS;
    __syncthreads();
    for (int off = 1; off < 256; off <<= 1) {
        int tP = (tid >= off) ? eP[tid - off] : 0;
        int tS = (tid >= off) ? eS[tid - off] : 0;
        __syncthreads();
        eP[tid] += tP; eS[tid] += tS;
        __syncthreads();
    }
    eP[tid] -= vP; eS[tid] -= vS;   // exclusive
    __syncthreads();

    // reserve global space (2 atomics per nonempty bin per block)
    if (tid < nbins) {
        gP[tid] = vP ? atomicAdd(&bincnt[tid], vP) : 0;
        gS[tid] = vS ? atomicAdd(&sbincnt[tid], vS) : 0;
    }
    __syncthreads();

    // pass 2: re-read edges (L2-hot), scatter into LDS bin-sorted order
    for (int t = tid; t < cnt; t += 256) {
        int s = src[e0 + t];
        int d = dst[e0 + t];
        int bp = d >> NPB_SHIFT;
        int r = atomicAdd(&rP[bp], 1);
        s_pair[eP[bp] + r] = PACK(s, d & (NPB - 1));
        int bs = s >> NPB_SHIFT;
        int r2 = atomicAdd(&rS[bs], 1);
        s_srcv[eS[bs] + r2] = s;
    }
    __syncthreads();

    // cooperative write-out: pairs (bin via 8-step binary search on eP)
    for (int t = tid; t < cnt; t += 256) {
        int lo = 0, hi = 255;
        while (lo < hi) {
            int mid = (lo + hi + 1) >> 1;
            if (eP[mid] <= t) lo = mid; else hi = mid - 1;
        }
        int off = gP[lo] + (t - eP[lo]);
        if (off < BINCAP)
            gpairs[(size_t)lo * BINCAP + off] = s_pair[t];
    }
    // cooperative write-out: srcs (bin from value)
    for (int t = tid; t < cnt; t += 256) {
        int v = s_srcv[t];
        int b = v >> NPB_SHIFT;
        int off = gS[b] + (t - eS[b]);
        if (off < SBINCAP)
            gsrc[(size_t)b * SBINCAP + off] = v;
    }
}

// ---- per-bin col window base (8-aligned, with pad slack) ----
__global__ void binscan_kernel(const int* __restrict__ bincnt,
                               int* __restrict__ colbase, int nbins, int N) {
    if (threadIdx.x == 0) {
        int a = 0;
        for (int b = 0; b < nbins; ++b) {
            colbase[b] = a;
            int node0 = b << NPB_SHIFT;
            int nn = N - node0; if (nn > NPB) nn = NPB;
            a += bincnt[b] + 7 * nn;
            a = (a + 7) & ~7;
        }
    }
}

// ================= Phase B: per-bin CSR build (rows padded to 8) ===========
// NOTE: indeg[] output holds the PADDED degree (multiple of 8); dnorm09 uses
// the real degree.
__global__ __launch_bounds__(256) void binB_kernel(
        const unsigned* __restrict__ gpairs, const int* __restrict__ bincnt,
        const int* __restrict__ colbase, int* __restrict__ row_start,
        int* __restrict__ indeg, float* __restrict__ dnorm09,
        int* __restrict__ col, int N) {
    __shared__ int s_hist[NPB];   // counts -> cursors
    __shared__ int s_pend[NPB];   // padded end offsets
    __shared__ int s_part[256];

    int b = blockIdx.x;
    int tid = threadIdx.x;
    int cnt = bincnt[b]; if (cnt > BINCAP) cnt = BINCAP;
    int cb = colbase[b];
    int node0 = b << NPB_SHIFT;
    int nn = N - node0; if (nn > NPB) nn = NPB;

    for (int t = tid; t < NPB; t += 256) s_hist[t] = 0;
    __syncthreads();

    const unsigned* bp = gpairs + (size_t)b * BINCAP;
    for (int t = tid; t < cnt; t += 256)
        atomicAdd(&s_hist[UNPACK_LOC(bp[t])], 1);
    __syncthreads();

    // degree outputs: padded degree into indeg, real degree into dnorm
    for (int t = tid; t < nn; t += 256) {
        int h = s_hist[t];
        indeg[node0 + t] = (h + 7) & ~7;
        int hh = h < 1 ? 1 : h;
        dnorm09[node0 + t] = (1.0f - ALPHA) * rsqrtf((float)hh);
    }

    // exclusive scan of PADDED lengths (2 slots/thread)
    int base = tid * 2;
    int h0 = s_hist[base], h1 = s_hist[base + 1];
    int p0 = (h0 + 7) & ~7, p1 = (h1 + 7) & ~7;
    int lsum = p0 + p1;
    s_part[tid] = lsum;
    __syncthreads();
    for (int off = 1; off < 256; off <<= 1) {
        int t2 = (tid >= off) ? s_part[tid - off] : 0;
        __syncthreads();
        s_part[tid] += t2;
        __syncthreads();
    }
    int run = s_part[tid] - lsum;   // exclusive base for slot base
    __syncthreads();
    s_hist[base]     = run;         // cursor (starts at padded-exclusive base)
    s_pend[base]     = run + p0;    // padded end
    s_hist[base + 1] = run + p0;
    s_pend[base + 1] = run + p0 + p1;
    if (base < nn)     row_start[node0 + base]     = cb + run;
    if (base + 1 < nn) row_start[node0 + base + 1] = cb + run + p0;
    __syncthreads();

    // scatter real cols
    for (int t = tid; t < cnt; t += 256) {
        unsigned pv = bp[t];
        int r = atomicAdd(&s_hist[UNPACK_LOC(pv)], 1);
        col[cb + r] = UNPACK_SRC(pv);
    }
    __syncthreads();

    // fill pads with sentinel node N (zero features)
    for (int t = tid; t < nn; t += 256) {
        for (int k = s_hist[t]; k < s_pend[t]; ++k) col[cb + k] = N;
    }
}

// ================= Phase B': per-bin outdeg -> snorm =======================
__global__ __launch_bounds__(256) void binBs_kernel(
        const int* __restrict__ gsrc, const int* __restrict__ sbincnt,
        float* __restrict__ snorm, int N) {
    __shared__ int s_hist[NPB];
    int b = blockIdx.x;
    int tid = threadIdx.x;
    int cnt = sbincnt[b]; if (cnt > SBINCAP) cnt = SBINCAP;
    int node0 = b << NPB_SHIFT;
    int nn = N - node0; if (nn > NPB) nn = NPB;

    for (int t = tid; t < NPB; t += 256) s_hist[t] = 0;
    __syncthreads();
    const int* sp = gsrc + (size_t)b * SBINCAP;
    for (int t = tid; t < cnt; t += 256)
        atomicAdd(&s_hist[sp[t] & (NPB - 1)], 1);
    __syncthreads();
    for (int t = tid; t < nn; t += 256) {
        int h = s_hist[t]; if (h < 1) h = 1;
        snorm[node0 + t] = rsqrtf((float)h);
    }
}

// ---- init: H0 = fp16(feat*snorm) @ stride HS, F0h = fp16(ALPHA*feat) dense
__global__ void init_kernel(const float4* __restrict__ feat0, const float* __restrict__ snorm,
                            uint4* __restrict__ H0, uint4* __restrict__ H1,
                            uint4* __restrict__ F0h, int N) {
    int i = blockIdx.x * blockDim.x + threadIdx.x;
    int total = N * NH;
    if (i >= total) {
        int j = i - total;   // sentinel row (node N): zero all HS chunks
        if (j < HS) {
            uint4 z = make_uint4(0, 0, 0, 0);
            H0[(size_t)N * HS + j] = z;
            H1[(size_t)N * HS + j] = z;
        }
        return;
    }
    int node = i / NH;
    int q = i - node * NH;
    float s = snorm[node];
    float4 a = feat0[i * 2];
    float4 b = feat0[i * 2 + 1];
    uint4 o;
    o.x = pack2(a.x * s, a.y * s);
    o.y = pack2(a.z * s, a.w * s);
    o.z = pack2(b.x * s, b.y * s);
    o.w = pack2(b.z * s, b.w * s);
    H0[(size_t)node * HS + q] = o;
    uint4 f;
    f.x = pack2(a.x * ALPHA, a.y * ALPHA);
    f.y = pack2(a.z * ALPHA, a.w * ALPHA);
    f.z = pack2(b.x * ALPHA, b.y * ALPHA);
    f.w = pack2(b.z * ALPHA, b.w * ALPHA);
    F0h[i] = f;
}

// ---- one propagation step: grouped 4+4 gather, col prefetch, <=64 VGPR ----
template <int LAST>
__global__ __launch_bounds__(256, 8) void step_kernel(
        const uint4* __restrict__ fin, const uint4* __restrict__ F0h,
        const int* __restrict__ row_start, const int* __restrict__ plen,
        const int* __restrict__ col, const float* __restrict__ snorm,
        const float* __restrict__ dnorm09,
        uint4* __restrict__ fout, float4* __restrict__ foutF, int n /* N */) {
    int tid = blockIdx.x * blockDim.x + threadIdx.x;
    if (tid >= n * NH) return;
    int node = tid / NH;
    int q = tid - node * NH;
    int rs = row_start[node];            // multiple of 8
    int p = plen[node];                  // padded degree (multiple of 8)
    const int4* col4 = (const int4*)(col + rs);   // 16B-aligned
    float acc[8] = {0.f, 0.f, 0.f, 0.f, 0.f, 0.f, 0.f, 0.f};
    if (p > 0) {
        int4 c0 = col4[0];
        int4 c1 = col4[1];
        int j = 8;
        while (true) {
            // group 1: 4 gathers in flight
            uint4 v0 = fin[((size_t)c0.x << 3) + q];
            uint4 v1 = fin[((size_t)c0.y << 3) + q];
            uint4 v2 = fin[((size_t)c0.z << 3) + q];
            uint4 v3 = fin[((size_t)c0.w << 3) + q];
            // prefetch next iteration's col pair during the gathers
            bool more = (j < p);
            int4 n0, n1;
            if (more) { n0 = col4[j >> 2]; n1 = col4[(j >> 2) + 1]; }
            add8(acc, v0); add8(acc, v1); add8(acc, v2); add8(acc, v3);
            // group 2
            uint4 v4 = fin[((size_t)c1.x << 3) + q];
            uint4 v5 = fin[((size_t)c1.y << 3) + q];
            uint4 v6 = fin[((size_t)c1.z << 3) + q];
            uint4 v7 = fin[((size_t)c1.w << 3) + q];
            add8(acc, v4); add8(acc, v5); add8(acc, v6); add8(acc, v7);
            if (!more) break;
            c0 = n0; c1 = n1; j += 8;
        }
    }
    float dn = dnorm09[node];
    uint4 f0 = F0h[tid];
    float2 t0 = unpack2(f0.x), t1 = unpack2(f0.y), t2 = unpack2(f0.z), t3 = unpack2(f0.w);
    float r[8];
    r[0] = acc[0] * dn + t0.x;
    r[1] = acc[1] * dn + t0.y;
    r[2] = acc[2] * dn + t1.x;
    r[3] = acc[3] * dn + t1.y;
    r[4] = acc[4] * dn + t2.x;
    r[5] = acc[5] * dn + t2.y;
    r[6] = acc[6] * dn + t3.x;
    r[7] = acc[7] * dn + t3.y;
    if (LAST) {
        float4 oa, ob;
        oa.x = r[0]; oa.y = r[1]; oa.z = r[2]; oa.w = r[3];
        ob.x = r[4]; ob.y = r[5]; ob.z = r[6]; ob.w = r[7];
        foutF[tid * 2]     = oa;
        foutF[tid * 2 + 1] = ob;
    } else {
        float sn = snorm[node];
        uint4 o;
        o.x = pack2(r[0] * sn, r[1] * sn);
        o.y = pack2(r[2] * sn, r[3] * sn);
        o.z = pack2(r[4] * sn, r[5] * sn);
        o.w = pack2(r[6] * sn, r[7] * sn);
        fout[(size_t)node * HS + q] = o;
    }
}

extern "C" void kernel_launch(void* const* d_in, const int* in_sizes, int n_in,
                              void* d_out, int out_size, void* d_ws, size_t ws_size,
                              hipStream_t stream) {
    const float* features = (const float*)d_in[0];
    const int*   src      = (const int*)d_in[1];
    const int*   dst      = (const int*)d_in[2];
    float*       out      = (float*)d_out;

    const int N = in_sizes[0] / ND;
    const int E = in_sizes[1];
    const int nbins = (N + NPB - 1) >> NPB_SHIFT;   // 196 for N=100000

    // ---- workspace layout (256B-aligned slices) ----
    char* w = (char*)d_ws;
    auto alloc = [&](size_t bytes) -> void* {
        void* p = (void*)w;
        w += (bytes + 255) & ~(size_t)255;
        return p;
    };
    uint4* H0       = (uint4*)alloc((size_t)(N + 1) * HS * sizeof(uint4));   // 12.8 MB
    uint4* H1       = (uint4*)alloc((size_t)(N + 1) * HS * sizeof(uint4));   // 12.8 MB
    uint4* F0h      = (uint4*)alloc((size_t)N * NH * sizeof(uint4));         // 9.6 MB
    int* col        = (int*)alloc(((size_t)E + 7 * (size_t)N + 8 * nbins) * sizeof(int)); // 9.2 MB
    unsigned* gpairs= (unsigned*)alloc((size_t)nbins * BINCAP * sizeof(unsigned)); // 8 MB
    int* gsrc       = (int*)alloc((size_t)nbins * SBINCAP * sizeof(int));          // 8 MB
    int* row_start  = (int*)alloc((size_t)N * sizeof(int));
    int* indeg      = (int*)alloc((size_t)N * sizeof(int));
    float* snorm    = (float*)alloc((size_t)N * sizeof(float));
    float* dnorm09  = (float*)alloc((size_t)N * sizeof(float));
    int* bincnt     = (int*)alloc((size_t)MAXBINS * sizeof(int));
    int* sbincnt    = (int*)alloc((size_t)MAXBINS * sizeof(int));
    int* colbase    = (int*)alloc((size_t)MAXBINS * sizeof(int));

    hipMemsetAsync(bincnt, 0, (size_t)MAXBINS * sizeof(int), stream);
    hipMemsetAsync(sbincnt, 0, (size_t)MAXBINS * sizeof(int), stream);

    const int gridB  = (E + CHB - 1) / CHB;      // 782
    const int total = N * NH;
    const int gridI = (total + HS + 255) / 256;  // covers sentinel row
    const int gridS = (total + 255) / 256;

    bin_kernel<<<gridB, 256, 0, stream>>>(src, dst, E, gpairs, bincnt,
                                          gsrc, sbincnt, nbins);
    binscan_kernel<<<1, 64, 0, stream>>>(bincnt, colbase, nbins, N);
    binB_kernel <<<nbins, 256, 0, stream>>>(gpairs, bincnt, colbase,
                                            row_start, indeg, dnorm09, col, N);
    binBs_kernel<<<nbins, 256, 0, stream>>>(gsrc, sbincnt, snorm, N);

    init_kernel<<<gridI, 256, 0, stream>>>((const float4*)features, snorm,
                                           H0, H1, F0h, N);

    for (int k = 0; k < KSTEPS; ++k) {
        const uint4* fin = (k & 1) ? (const uint4*)H1 : (const uint4*)H0;
        uint4*       fo  = (k & 1) ? H0 : H1;
        if (k == KSTEPS - 1) {
            step_kernel<1><<<gridS, 256, 0, stream>>>(
                fin, F0h, row_start, indeg, col, snorm, dnorm09,
                fo, (float4*)out, N);
        } else {
            step_kernel<0><<<gridS, 256, 0, stream>>>(
                fin, F0h, row_start, indeg, col, snorm, dnorm09,
                fo, nullptr, N);
        }
    }
}

// Round 11
// 460.943 us; speedup vs baseline: 2.3491x; 2.3491x over previous
//
#include <hip/hip_runtime.h>
#include <hip/hip_fp16.h>

#define ND 48       // feature dim (floats)
#define NH 6        // used uint4 chunks per row (48/8)
#define HS 8        // row stride in uint4 (128B-aligned rows)
#define KSTEPS 10
#define ALPHA 0.1f

#define NPB_SHIFT 9
#define NPB 512             // nodes per bin
#define MAXBINS 256         // supports N <= 131072
#define CHB 2048            // edges per block, merged bin kernel
#define BINCAP 10240        // pair capacity per bin (mean 8163, +23 sigma)
#define SBINCAP 10240

// pack (src, dstLocal) into 4B: dstLocal<<18 | src   (src < 2^18, dstLocal < 2^9)
#define PACK(s, dl) (((unsigned)(dl) << 18) | (unsigned)(s))
#define UNPACK_SRC(v) ((int)((v) & 0x3FFFFu))
#define UNPACK_LOC(v) ((int)((v) >> 18))

// ---- fp16 pack/unpack helpers ----
__device__ inline float2 unpack2(unsigned int u) {
    __half2 h;
    *reinterpret_cast<unsigned int*>(&h) = u;
    return __half22float2(h);
}
__device__ inline unsigned int pack2(float x, float y) {
    __half2 h = __floats2half2_rn(x, y);
    return *reinterpret_cast<unsigned int*>(&h);
}
__device__ inline void add8(float* a, uint4 v) {
    float2 t;
    t = unpack2(v.x); a[0] += t.x; a[1] += t.y;
    t = unpack2(v.y); a[2] += t.x; a[3] += t.y;
    t = unpack2(v.z); a[4] += t.x; a[5] += t.y;
    t = unpack2(v.w); a[6] += t.x; a[7] += t.y;
}

// ========== merged binning: dst-binned packed pairs + src-binned values ====
__global__ __launch_bounds__(256) void bin_kernel(
        const int* __restrict__ src, const int* __restrict__ dst, int E,
        unsigned* __restrict__ gpairs, int* __restrict__ bincnt,
        int* __restrict__ gsrc, int* __restrict__ sbincnt, int nbins) {
    __shared__ unsigned s_pair[CHB];   // 8 KB
    __shared__ int s_srcv[CHB];        // 8 KB
    __shared__ int hP[MAXBINS], eP[MAXBINS], rP[MAXBINS], gP[MAXBINS];
    __shared__ int hS[MAXBINS], eS[MAXBINS], rS[MAXBINS], gS[MAXBINS];

    int tid = threadIdx.x;
    int e0 = blockIdx.x * CHB;
    int cnt = E - e0; if (cnt > CHB) cnt = CHB;

    hP[tid] = 0; rP[tid] = 0; hS[tid] = 0; rS[tid] = 0;
    __syncthreads();

    // pass 1: dual histogram
    for (int t = tid; t < cnt; t += 256) {
        atomicAdd(&hP[dst[e0 + t] >> NPB_SHIFT], 1);
        atomicAdd(&hS[src[e0 + t] >> NPB_SHIFT], 1);
    }
    __syncthreads();

    // dual exclusive scan over 256 bins
    int vP = hP[tid], vS = hS[tid];
    eP[tid] = vP; eS[tid] = vS;
    __syncthreads();
    for (int off = 1; off < 256; off <<= 1) {
        int tP = (tid >= off) ? eP[tid - off] : 0;
        int tS = (tid >= off) ? eS[tid - off] : 0;
        __syncthreads();
        eP[tid] += tP; eS[tid] += tS;
        __syncthreads();
    }
    eP[tid] -= vP; eS[tid] -= vS;   // exclusive
    __syncthreads();

    // reserve global space (2 atomics per nonempty bin per block)
    if (tid < nbins) {
        gP[tid] = vP ? atomicAdd(&bincnt[tid], vP) : 0;
        gS[tid] = vS ? atomicAdd(&sbincnt[tid], vS) : 0;
    }
    __syncthreads();

    // pass 2: re-read edges (L2-hot), scatter into LDS bin-sorted order
    for (int t = tid; t < cnt; t += 256) {
        int s = src[e0 + t];
        int d = dst[e0 + t];
        int bp = d >> NPB_SHIFT;
        int r = atomicAdd(&rP[bp], 1);
        s_pair[eP[bp] + r] = PACK(s, d & (NPB - 1));
        int bs = s >> NPB_SHIFT;
        int r2 = atomicAdd(&rS[bs], 1);
        s_srcv[eS[bs] + r2] = s;
    }
    __syncthreads();

    // cooperative write-out: pairs (bin via 8-step binary search on eP)
    for (int t = tid; t < cnt; t += 256) {
        int lo = 0, hi = 255;
        while (lo < hi) {
            int mid = (lo + hi + 1) >> 1;
            if (eP[mid] <= t) lo = mid; else hi = mid - 1;
        }
        int off = gP[lo] + (t - eP[lo]);
        if (off < BINCAP)
            gpairs[(size_t)lo * BINCAP + off] = s_pair[t];
    }
    // cooperative write-out: srcs (bin from value)
    for (int t = tid; t < cnt; t += 256) {
        int v = s_srcv[t];
        int b = v >> NPB_SHIFT;
        int off = gS[b] + (t - eS[b]);
        if (off < SBINCAP)
            gsrc[(size_t)b * SBINCAP + off] = v;
    }
}

// ---- per-bin col window base (8-aligned, with pad slack) ----
__global__ void binscan_kernel(const int* __restrict__ bincnt,
                               int* __restrict__ colbase, int nbins, int N) {
    if (threadIdx.x == 0) {
        int a = 0;
        for (int b = 0; b < nbins; ++b) {
            colbase[b] = a;
            int node0 = b << NPB_SHIFT;
            int nn = N - node0; if (nn > NPB) nn = NPB;
            a += bincnt[b] + 7 * nn;
            a = (a + 7) & ~7;
        }
    }
}

// ================= Phase B: per-bin CSR build (rows padded to 8) ===========
// NOTE: indeg[] output holds the PADDED degree (multiple of 8); dnorm09 uses
// the real degree.
__global__ __launch_bounds__(256) void binB_kernel(
        const unsigned* __restrict__ gpairs, const int* __restrict__ bincnt,
        const int* __restrict__ colbase, int* __restrict__ row_start,
        int* __restrict__ indeg, float* __restrict__ dnorm09,
        int* __restrict__ col, int N) {
    __shared__ int s_hist[NPB];   // counts -> cursors
    __shared__ int s_pend[NPB];   // padded end offsets
    __shared__ int s_part[256];

    int b = blockIdx.x;
    int tid = threadIdx.x;
    int cnt = bincnt[b]; if (cnt > BINCAP) cnt = BINCAP;
    int cb = colbase[b];
    int node0 = b << NPB_SHIFT;
    int nn = N - node0; if (nn > NPB) nn = NPB;

    for (int t = tid; t < NPB; t += 256) s_hist[t] = 0;
    __syncthreads();

    const unsigned* bp = gpairs + (size_t)b * BINCAP;
    for (int t = tid; t < cnt; t += 256)
        atomicAdd(&s_hist[UNPACK_LOC(bp[t])], 1);
    __syncthreads();

    // degree outputs: padded degree into indeg, real degree into dnorm
    for (int t = tid; t < nn; t += 256) {
        int h = s_hist[t];
        indeg[node0 + t] = (h + 7) & ~7;
        int hh = h < 1 ? 1 : h;
        dnorm09[node0 + t] = (1.0f - ALPHA) * rsqrtf((float)hh);
    }

    // exclusive scan of PADDED lengths (2 slots/thread)
    int base = tid * 2;
    int h0 = s_hist[base], h1 = s_hist[base + 1];
    int p0 = (h0 + 7) & ~7, p1 = (h1 + 7) & ~7;
    int lsum = p0 + p1;
    s_part[tid] = lsum;
    __syncthreads();
    for (int off = 1; off < 256; off <<= 1) {
        int t2 = (tid >= off) ? s_part[tid - off] : 0;
        __syncthreads();
        s_part[tid] += t2;
        __syncthreads();
    }
    int run = s_part[tid] - lsum;   // exclusive base for slot base
    __syncthreads();
    s_hist[base]     = run;         // cursor (starts at padded-exclusive base)
    s_pend[base]     = run + p0;    // padded end
    s_hist[base + 1] = run + p0;
    s_pend[base + 1] = run + p0 + p1;
    if (base < nn)     row_start[node0 + base]     = cb + run;
    if (base + 1 < nn) row_start[node0 + base + 1] = cb + run + p0;
    __syncthreads();

    // scatter real cols
    for (int t = tid; t < cnt; t += 256) {
        unsigned pv = bp[t];
        int r = atomicAdd(&s_hist[UNPACK_LOC(pv)], 1);
        col[cb + r] = UNPACK_SRC(pv);
    }
    __syncthreads();

    // fill pads with sentinel node N (zero features)
    for (int t = tid; t < nn; t += 256) {
        for (int k = s_hist[t]; k < s_pend[t]; ++k) col[cb + k] = N;
    }
}

// ================= Phase B': per-bin outdeg -> snorm =======================
__global__ __launch_bounds__(256) void binBs_kernel(
        const int* __restrict__ gsrc, const int* __restrict__ sbincnt,
        float* __restrict__ snorm, int N) {
    __shared__ int s_hist[NPB];
    int b = blockIdx.x;
    int tid = threadIdx.x;
    int cnt = sbincnt[b]; if (cnt > SBINCAP) cnt = SBINCAP;
    int node0 = b << NPB_SHIFT;
    int nn = N - node0; if (nn > NPB) nn = NPB;

    for (int t = tid; t < NPB; t += 256) s_hist[t] = 0;
    __syncthreads();
    const int* sp = gsrc + (size_t)b * SBINCAP;
    for (int t = tid; t < cnt; t += 256)
        atomicAdd(&s_hist[sp[t] & (NPB - 1)], 1);
    __syncthreads();
    for (int t = tid; t < nn; t += 256) {
        int h = s_hist[t]; if (h < 1) h = 1;
        snorm[node0 + t] = rsqrtf((float)h);
    }
}

// ---- init: H0 = fp16(feat*snorm) @ stride HS, F0h = fp16(ALPHA*feat) dense
__global__ void init_kernel(const float4* __restrict__ feat0, const float* __restrict__ snorm,
                            uint4* __restrict__ H0, uint4* __restrict__ H1,
                            uint4* __restrict__ F0h, int N) {
    int i = blockIdx.x * blockDim.x + threadIdx.x;
    int total = N * NH;
    if (i >= total) {
        int j = i - total;   // sentinel row (node N): zero all HS chunks
        if (j < HS) {
            uint4 z = make_uint4(0, 0, 0, 0);
            H0[(size_t)N * HS + j] = z;
            H1[(size_t)N * HS + j] = z;
        }
        return;
    }
    int node = i / NH;
    int q = i - node * NH;
    float s = snorm[node];
    float4 a = feat0[i * 2];
    float4 b = feat0[i * 2 + 1];
    uint4 o;
    o.x = pack2(a.x * s, a.y * s);
    o.y = pack2(a.z * s, a.w * s);
    o.z = pack2(b.x * s, b.y * s);
    o.w = pack2(b.z * s, b.w * s);
    H0[(size_t)node * HS + q] = o;
    uint4 f;
    f.x = pack2(a.x * ALPHA, a.y * ALPHA);
    f.y = pack2(a.z * ALPHA, a.w * ALPHA);
    f.z = pack2(b.x * ALPHA, b.y * ALPHA);
    f.w = pack2(b.z * ALPHA, b.w * ALPHA);
    F0h[i] = f;
}

// ---- one propagation step: branch-free 8-wide gather (round-9 form) ----
// plen[] holds padded degree (multiple of 8); no VGPR clamp (round-10's
// (256,8) clamp forced 32 VGPR -> scratch spill, 159 MB/step writes, 2.8x slower).
template <int LAST>
__global__ __launch_bounds__(256) void step_kernel(
        const uint4* __restrict__ fin, const uint4* __restrict__ F0h,
        const int* __restrict__ row_start, const int* __restrict__ plen,
        const int* __restrict__ col, const float* __restrict__ snorm,
        const float* __restrict__ dnorm09,
        uint4* __restrict__ fout, float4* __restrict__ foutF, int n /* N */) {
    int tid = blockIdx.x * blockDim.x + threadIdx.x;
    if (tid >= n * NH) return;
    int node = tid / NH;
    int q = tid - node * NH;
    int rs = row_start[node];            // multiple of 8
    int p = plen[node];                  // padded degree (multiple of 8)
    const int4* col4 = (const int4*)(col + rs);   // 16B-aligned
    float acc[8] = {0.f, 0.f, 0.f, 0.f, 0.f, 0.f, 0.f, 0.f};
    for (int j = 0; j < p; j += 8) {
        int4 c0 = col4[j >> 2];
        int4 c1 = col4[(j >> 2) + 1];
        uint4 v0 = fin[((size_t)c0.x << 3) + q];
        uint4 v1 = fin[((size_t)c0.y << 3) + q];
        uint4 v2 = fin[((size_t)c0.z << 3) + q];
        uint4 v3 = fin[((size_t)c0.w << 3) + q];
        uint4 v4 = fin[((size_t)c1.x << 3) + q];
        uint4 v5 = fin[((size_t)c1.y << 3) + q];
        uint4 v6 = fin[((size_t)c1.z << 3) + q];
        uint4 v7 = fin[((size_t)c1.w << 3) + q];
        add8(acc, v0); add8(acc, v1); add8(acc, v2); add8(acc, v3);
        add8(acc, v4); add8(acc, v5); add8(acc, v6); add8(acc, v7);
    }
    float dn = dnorm09[node];
    uint4 f0 = F0h[tid];
    float2 t0 = unpack2(f0.x), t1 = unpack2(f0.y), t2 = unpack2(f0.z), t3 = unpack2(f0.w);
    float r[8];
    r[0] = acc[0] * dn + t0.x;
    r[1] = acc[1] * dn + t0.y;
    r[2] = acc[2] * dn + t1.x;
    r[3] = acc[3] * dn + t1.y;
    r[4] = acc[4] * dn + t2.x;
    r[5] = acc[5] * dn + t2.y;
    r[6] = acc[6] * dn + t3.x;
    r[7] = acc[7] * dn + t3.y;
    if (LAST) {
        float4 oa, ob;
        oa.x = r[0]; oa.y = r[1]; oa.z = r[2]; oa.w = r[3];
        ob.x = r[4]; ob.y = r[5]; ob.z = r[6]; ob.w = r[7];
        foutF[tid * 2]     = oa;
        foutF[tid * 2 + 1] = ob;
    } else {
        float sn = snorm[node];
        uint4 o;
        o.x = pack2(r[0] * sn, r[1] * sn);
        o.y = pack2(r[2] * sn, r[3] * sn);
        o.z = pack2(r[4] * sn, r[5] * sn);
        o.w = pack2(r[6] * sn, r[7] * sn);
        fout[(size_t)node * HS + q] = o;
    }
}

extern "C" void kernel_launch(void* const* d_in, const int* in_sizes, int n_in,
                              void* d_out, int out_size, void* d_ws, size_t ws_size,
                              hipStream_t stream) {
    const float* features = (const float*)d_in[0];
    const int*   src      = (const int*)d_in[1];
    const int*   dst      = (const int*)d_in[2];
    float*       out      = (float*)d_out;

    const int N = in_sizes[0] / ND;
    const int E = in_sizes[1];
    const int nbins = (N + NPB - 1) >> NPB_SHIFT;   // 196 for N=100000

    // ---- workspace layout (256B-aligned slices) ----
    char* w = (char*)d_ws;
    auto alloc = [&](size_t bytes) -> void* {
        void* p = (void*)w;
        w += (bytes + 255) & ~(size_t)255;
        return p;
    };
    uint4* H0       = (uint4*)alloc((size_t)(N + 1) * HS * sizeof(uint4));   // 12.8 MB
    uint4* H1       = (uint4*)alloc((size_t)(N + 1) * HS * sizeof(uint4));   // 12.8 MB
    uint4* F0h      = (uint4*)alloc((size_t)N * NH * sizeof(uint4));         // 9.6 MB
    int* col        = (int*)alloc(((size_t)E + 7 * (size_t)N + 8 * nbins) * sizeof(int)); // 9.2 MB
    unsigned* gpairs= (unsigned*)alloc((size_t)nbins * BINCAP * sizeof(unsigned)); // 8 MB
    int* gsrc       = (int*)alloc((size_t)nbins * SBINCAP * sizeof(int));          // 8 MB
    int* row_start  = (int*)alloc((size_t)N * sizeof(int));
    int* indeg      = (int*)alloc((size_t)N * sizeof(int));
    float* snorm    = (float*)alloc((size_t)N * sizeof(float));
    float* dnorm09  = (float*)alloc((size_t)N * sizeof(float));
    int* bincnt     = (int*)alloc((size_t)MAXBINS * sizeof(int));
    int* sbincnt    = (int*)alloc((size_t)MAXBINS * sizeof(int));
    int* colbase    = (int*)alloc((size_t)MAXBINS * sizeof(int));

    hipMemsetAsync(bincnt, 0, (size_t)MAXBINS * sizeof(int), stream);
    hipMemsetAsync(sbincnt, 0, (size_t)MAXBINS * sizeof(int), stream);

    const int gridB  = (E + CHB - 1) / CHB;      // 782
    const int total = N * NH;
    const int gridI = (total + HS + 255) / 256;  // covers sentinel row
    const int gridS = (total + 255) / 256;

    bin_kernel<<<gridB, 256, 0, stream>>>(src, dst, E, gpairs, bincnt,
                                          gsrc, sbincnt, nbins);
    binscan_kernel<<<1, 64, 0, stream>>>(bincnt, colbase, nbins, N);
    binB_kernel <<<nbins, 256, 0, stream>>>(gpairs, bincnt, colbase,
                                            row_start, indeg, dnorm09, col, N);
    binBs_kernel<<<nbins, 256, 0, stream>>>(gsrc, sbincnt, snorm, N);

    init_kernel<<<gridI, 256, 0, stream>>>((const float4*)features, snorm,
                                           H0, H1, F0h, N);

    for (int k = 0; k < KSTEPS; ++k) {
        const uint4* fin = (k & 1) ? (const uint4*)H1 : (const uint4*)H0;
        uint4*       fo  = (k & 1) ? H0 : H1;
        if (k == KSTEPS - 1) {
            step_kernel<1><<<gridS, 256, 0, stream>>>(
                fin, F0h, row_start, indeg, col, snorm, dnorm09,
                fo, (float4*)out, N);
        } else {
            step_kernel<0><<<gridS, 256, 0, stream>>>(
                fin, F0h, row_start, indeg, col, snorm, dnorm09,
                fo, nullptr, N);
        }
    }
}

// Round 12
// 452.282 us; speedup vs baseline: 2.3941x; 1.0191x over previous
//
#include <hip/hip_runtime.h>
#include <hip/hip_fp16.h>

#define ND 48       // feature dim (floats)
#define NH 6        // used uint4 chunks per row (48/8)
#define HS 8        // row stride in uint4 (128B-aligned rows)
#define KSTEPS 10
#define ALPHA 0.1f

#define NPB_SHIFT 9
#define NPB 512             // nodes per bin
#define MAXBINS 256         // supports N <= 131072
#define CHB 2048            // edges per block, merged bin kernel
#define BINCAP 10240        // pair capacity per bin (mean 8163, +23 sigma)
#define SBINCAP 10240

// pack (src, dstLocal) into 4B: dstLocal<<18 | src   (src < 2^18, dstLocal < 2^9)
#define PACK(s, dl) (((unsigned)(dl) << 18) | (unsigned)(s))
#define UNPACK_SRC(v) ((int)((v) & 0x3FFFFu))
#define UNPACK_LOC(v) ((int)((v) >> 18))

// ---- fp16 pack/unpack helpers ----
__device__ inline float2 unpack2(unsigned int u) {
    __half2 h;
    *reinterpret_cast<unsigned int*>(&h) = u;
    return __half22float2(h);
}
__device__ inline unsigned int pack2(float x, float y) {
    __half2 h = __floats2half2_rn(x, y);
    return *reinterpret_cast<unsigned int*>(&h);
}
__device__ inline void add8(float* a, uint4 v) {
    float2 t;
    t = unpack2(v.x); a[0] += t.x; a[1] += t.y;
    t = unpack2(v.y); a[2] += t.x; a[3] += t.y;
    t = unpack2(v.z); a[4] += t.x; a[5] += t.y;
    t = unpack2(v.w); a[6] += t.x; a[7] += t.y;
}

// ========== merged binning: dst-binned packed pairs + src-binned values ====
__global__ __launch_bounds__(256) void bin_kernel(
        const int* __restrict__ src, const int* __restrict__ dst, int E,
        unsigned* __restrict__ gpairs, int* __restrict__ bincnt,
        int* __restrict__ gsrc, int* __restrict__ sbincnt, int nbins) {
    __shared__ unsigned s_pair[CHB];   // 8 KB
    __shared__ int s_srcv[CHB];        // 8 KB
    __shared__ int hP[MAXBINS], eP[MAXBINS], rP[MAXBINS], gP[MAXBINS];
    __shared__ int hS[MAXBINS], eS[MAXBINS], rS[MAXBINS], gS[MAXBINS];

    int tid = threadIdx.x;
    int e0 = blockIdx.x * CHB;
    int cnt = E - e0; if (cnt > CHB) cnt = CHB;

    hP[tid] = 0; rP[tid] = 0; hS[tid] = 0; rS[tid] = 0;
    __syncthreads();

    // pass 1: dual histogram
    for (int t = tid; t < cnt; t += 256) {
        atomicAdd(&hP[dst[e0 + t] >> NPB_SHIFT], 1);
        atomicAdd(&hS[src[e0 + t] >> NPB_SHIFT], 1);
    }
    __syncthreads();

    // dual exclusive scan over 256 bins
    int vP = hP[tid], vS = hS[tid];
    eP[tid] = vP; eS[tid] = vS;
    __syncthreads();
    for (int off = 1; off < 256; off <<= 1) {
        int tP = (tid >= off) ? eP[tid - off] : 0;
        int tS = (tid >= off) ? eS[tid - off] : 0;
        __syncthreads();
        eP[tid] += tP; eS[tid] += tS;
        __syncthreads();
    }
    eP[tid] -= vP; eS[tid] -= vS;   // exclusive
    __syncthreads();

    // reserve global space (2 atomics per nonempty bin per block)
    if (tid < nbins) {
        gP[tid] = vP ? atomicAdd(&bincnt[tid], vP) : 0;
        gS[tid] = vS ? atomicAdd(&sbincnt[tid], vS) : 0;
    }
    __syncthreads();

    // pass 2: re-read edges (L2-hot), scatter into LDS bin-sorted order
    for (int t = tid; t < cnt; t += 256) {
        int s = src[e0 + t];
        int d = dst[e0 + t];
        int bp = d >> NPB_SHIFT;
        int r = atomicAdd(&rP[bp], 1);
        s_pair[eP[bp] + r] = PACK(s, d & (NPB - 1));
        int bs = s >> NPB_SHIFT;
        int r2 = atomicAdd(&rS[bs], 1);
        s_srcv[eS[bs] + r2] = s;
    }
    __syncthreads();

    // cooperative write-out: pairs (bin via 8-step binary search on eP)
    for (int t = tid; t < cnt; t += 256) {
        int lo = 0, hi = 255;
        while (lo < hi) {
            int mid = (lo + hi + 1) >> 1;
            if (eP[mid] <= t) lo = mid; else hi = mid - 1;
        }
        int off = gP[lo] + (t - eP[lo]);
        if (off < BINCAP)
            gpairs[(size_t)lo * BINCAP + off] = s_pair[t];
    }
    // cooperative write-out: srcs (bin from value)
    for (int t = tid; t < cnt; t += 256) {
        int v = s_srcv[t];
        int b = v >> NPB_SHIFT;
        int off = gS[b] + (t - eS[b]);
        if (off < SBINCAP)
            gsrc[(size_t)b * SBINCAP + off] = v;
    }
}

// ---- per-bin col window base (8-aligned, with pad slack) ----
__global__ void binscan_kernel(const int* __restrict__ bincnt,
                               int* __restrict__ colbase, int nbins, int N) {
    if (threadIdx.x == 0) {
        int a = 0;
        for (int b = 0; b < nbins; ++b) {
            colbase[b] = a;
            int node0 = b << NPB_SHIFT;
            int nn = N - node0; if (nn > NPB) nn = NPB;
            a += bincnt[b] + 7 * nn;
            a = (a + 7) & ~7;
        }
    }
}

// ================= Phase B: per-bin CSR build (rows padded to 8) ===========
// NOTE: indeg[] output holds the PADDED degree (multiple of 8); dnorm09 uses
// the real degree.
__global__ __launch_bounds__(256) void binB_kernel(
        const unsigned* __restrict__ gpairs, const int* __restrict__ bincnt,
        const int* __restrict__ colbase, int* __restrict__ row_start,
        int* __restrict__ indeg, float* __restrict__ dnorm09,
        int* __restrict__ col, int N) {
    __shared__ int s_hist[NPB];   // counts -> cursors
    __shared__ int s_pend[NPB];   // padded end offsets
    __shared__ int s_part[256];

    int b = blockIdx.x;
    int tid = threadIdx.x;
    int cnt = bincnt[b]; if (cnt > BINCAP) cnt = BINCAP;
    int cb = colbase[b];
    int node0 = b << NPB_SHIFT;
    int nn = N - node0; if (nn > NPB) nn = NPB;

    for (int t = tid; t < NPB; t += 256) s_hist[t] = 0;
    __syncthreads();

    const unsigned* bp = gpairs + (size_t)b * BINCAP;
    for (int t = tid; t < cnt; t += 256)
        atomicAdd(&s_hist[UNPACK_LOC(bp[t])], 1);
    __syncthreads();

    // degree outputs: padded degree into indeg, real degree into dnorm
    for (int t = tid; t < nn; t += 256) {
        int h = s_hist[t];
        indeg[node0 + t] = (h + 7) & ~7;
        int hh = h < 1 ? 1 : h;
        dnorm09[node0 + t] = (1.0f - ALPHA) * rsqrtf((float)hh);
    }

    // exclusive scan of PADDED lengths (2 slots/thread)
    int base = tid * 2;
    int h0 = s_hist[base], h1 = s_hist[base + 1];
    int p0 = (h0 + 7) & ~7, p1 = (h1 + 7) & ~7;
    int lsum = p0 + p1;
    s_part[tid] = lsum;
    __syncthreads();
    for (int off = 1; off < 256; off <<= 1) {
        int t2 = (tid >= off) ? s_part[tid - off] : 0;
        __syncthreads();
        s_part[tid] += t2;
        __syncthreads();
    }
    int run = s_part[tid] - lsum;   // exclusive base for slot base
    __syncthreads();
    s_hist[base]     = run;         // cursor (starts at padded-exclusive base)
    s_pend[base]     = run + p0;    // padded end
    s_hist[base + 1] = run + p0;
    s_pend[base + 1] = run + p0 + p1;
    if (base < nn)     row_start[node0 + base]     = cb + run;
    if (base + 1 < nn) row_start[node0 + base + 1] = cb + run + p0;
    __syncthreads();

    // scatter real cols
    for (int t = tid; t < cnt; t += 256) {
        unsigned pv = bp[t];
        int r = atomicAdd(&s_hist[UNPACK_LOC(pv)], 1);
        col[cb + r] = UNPACK_SRC(pv);
    }
    __syncthreads();

    // fill pads with sentinel node N (zero features)
    for (int t = tid; t < nn; t += 256) {
        for (int k = s_hist[t]; k < s_pend[t]; ++k) col[cb + k] = N;
    }
}

// ================= Phase B': per-bin outdeg -> snorm =======================
__global__ __launch_bounds__(256) void binBs_kernel(
        const int* __restrict__ gsrc, const int* __restrict__ sbincnt,
        float* __restrict__ snorm, int N) {
    __shared__ int s_hist[NPB];
    int b = blockIdx.x;
    int tid = threadIdx.x;
    int cnt = sbincnt[b]; if (cnt > SBINCAP) cnt = SBINCAP;
    int node0 = b << NPB_SHIFT;
    int nn = N - node0; if (nn > NPB) nn = NPB;

    for (int t = tid; t < NPB; t += 256) s_hist[t] = 0;
    __syncthreads();
    const int* sp = gsrc + (size_t)b * SBINCAP;
    for (int t = tid; t < cnt; t += 256)
        atomicAdd(&s_hist[sp[t] & (NPB - 1)], 1);
    __syncthreads();
    for (int t = tid; t < nn; t += 256) {
        int h = s_hist[t]; if (h < 1) h = 1;
        snorm[node0 + t] = rsqrtf((float)h);
    }
}

// ---- init: H0 = fp16(feat*snorm) @ stride HS, F0h = fp16(ALPHA*feat) dense
__global__ void init_kernel(const float4* __restrict__ feat0, const float* __restrict__ snorm,
                            uint4* __restrict__ H0, uint4* __restrict__ H1,
                            uint4* __restrict__ F0h, int N) {
    int i = blockIdx.x * blockDim.x + threadIdx.x;
    int total = N * NH;
    if (i >= total) {
        int j = i - total;   // sentinel row (node N): zero all HS chunks
        if (j < HS) {
            uint4 z = make_uint4(0, 0, 0, 0);
            H0[(size_t)N * HS + j] = z;
            H1[(size_t)N * HS + j] = z;
        }
        return;
    }
    int node = i / NH;
    int q = i - node * NH;
    float s = snorm[node];
    float4 a = feat0[i * 2];
    float4 b = feat0[i * 2 + 1];
    uint4 o;
    o.x = pack2(a.x * s, a.y * s);
    o.y = pack2(a.z * s, a.w * s);
    o.z = pack2(b.x * s, b.y * s);
    o.w = pack2(b.z * s, b.w * s);
    H0[(size_t)node * HS + q] = o;
    uint4 f;
    f.x = pack2(a.x * ALPHA, a.y * ALPHA);
    f.y = pack2(a.z * ALPHA, a.w * ALPHA);
    f.z = pack2(b.x * ALPHA, b.y * ALPHA);
    f.w = pack2(b.z * ALPHA, b.w * ALPHA);
    F0h[i] = f;
}

// ---- one propagation step: 8-wide gather + col prefetch, NO VGPR clamp ----
// (round-10 body; round-10's regression was solely the (256,8) clamp -> 32
// VGPR -> scratch spill. Uncapped, expected ~56-64 VGPR, no spill.)
template <int LAST>
__global__ __launch_bounds__(256) void step_kernel(
        const uint4* __restrict__ fin, const uint4* __restrict__ F0h,
        const int* __restrict__ row_start, const int* __restrict__ plen,
        const int* __restrict__ col, const float* __restrict__ snorm,
        const float* __restrict__ dnorm09,
        uint4* __restrict__ fout, float4* __restrict__ foutF, int n /* N */) {
    int tid = blockIdx.x * blockDim.x + threadIdx.x;
    if (tid >= n * NH) return;
    int node = tid / NH;
    int q = tid - node * NH;
    int rs = row_start[node];            // multiple of 8
    int p = plen[node];                  // padded degree (multiple of 8)
    const int4* col4 = (const int4*)(col + rs);   // 16B-aligned
    float acc[8] = {0.f, 0.f, 0.f, 0.f, 0.f, 0.f, 0.f, 0.f};
    if (p > 0) {
        int4 c0 = col4[0];
        int4 c1 = col4[1];
        int j = 8;
        while (true) {
            // 8 gathers in flight
            uint4 v0 = fin[((size_t)c0.x << 3) + q];
            uint4 v1 = fin[((size_t)c0.y << 3) + q];
            uint4 v2 = fin[((size_t)c0.z << 3) + q];
            uint4 v3 = fin[((size_t)c0.w << 3) + q];
            uint4 v4 = fin[((size_t)c1.x << 3) + q];
            uint4 v5 = fin[((size_t)c1.y << 3) + q];
            uint4 v6 = fin[((size_t)c1.z << 3) + q];
            uint4 v7 = fin[((size_t)c1.w << 3) + q];
            // overlap next iteration's col pair with the gathers
            bool more = (j < p);
            int4 n0, n1;
            if (more) { n0 = col4[j >> 2]; n1 = col4[(j >> 2) + 1]; }
            add8(acc, v0); add8(acc, v1); add8(acc, v2); add8(acc, v3);
            add8(acc, v4); add8(acc, v5); add8(acc, v6); add8(acc, v7);
            if (!more) break;
            c0 = n0; c1 = n1; j += 8;
        }
    }
    float dn = dnorm09[node];
    uint4 f0 = F0h[tid];
    float2 t0 = unpack2(f0.x), t1 = unpack2(f0.y), t2 = unpack2(f0.z), t3 = unpack2(f0.w);
    float r[8];
    r[0] = acc[0] * dn + t0.x;
    r[1] = acc[1] * dn + t0.y;
    r[2] = acc[2] * dn + t1.x;
    r[3] = acc[3] * dn + t1.y;
    r[4] = acc[4] * dn + t2.x;
    r[5] = acc[5] * dn + t2.y;
    r[6] = acc[6] * dn + t3.x;
    r[7] = acc[7] * dn + t3.y;
    if (LAST) {
        float4 oa, ob;
        oa.x = r[0]; oa.y = r[1]; oa.z = r[2]; oa.w = r[3];
        ob.x = r[4]; ob.y = r[5]; ob.z = r[6]; ob.w = r[7];
        foutF[tid * 2]     = oa;
        foutF[tid * 2 + 1] = ob;
    } else {
        float sn = snorm[node];
        uint4 o;
        o.x = pack2(r[0] * sn, r[1] * sn);
        o.y = pack2(r[2] * sn, r[3] * sn);
        o.z = pack2(r[4] * sn, r[5] * sn);
        o.w = pack2(r[6] * sn, r[7] * sn);
        fout[(size_t)node * HS + q] = o;
    }
}

extern "C" void kernel_launch(void* const* d_in, const int* in_sizes, int n_in,
                              void* d_out, int out_size, void* d_ws, size_t ws_size,
                              hipStream_t stream) {
    const float* features = (const float*)d_in[0];
    const int*   src      = (const int*)d_in[1];
    const int*   dst      = (const int*)d_in[2];
    float*       out      = (float*)d_out;

    const int N = in_sizes[0] / ND;
    const int E = in_sizes[1];
    const int nbins = (N + NPB - 1) >> NPB_SHIFT;   // 196 for N=100000

    // ---- workspace layout (256B-aligned slices) ----
    char* w = (char*)d_ws;
    auto alloc = [&](size_t bytes) -> void* {
        void* p = (void*)w;
        w += (bytes + 255) & ~(size_t)255;
        return p;
    };
    uint4* H0       = (uint4*)alloc((size_t)(N + 1) * HS * sizeof(uint4));   // 12.8 MB
    uint4* H1       = (uint4*)alloc((size_t)(N + 1) * HS * sizeof(uint4));   // 12.8 MB
    uint4* F0h      = (uint4*)alloc((size_t)N * NH * sizeof(uint4));         // 9.6 MB
    int* col        = (int*)alloc(((size_t)E + 7 * (size_t)N + 8 * nbins) * sizeof(int)); // 9.2 MB
    unsigned* gpairs= (unsigned*)alloc((size_t)nbins * BINCAP * sizeof(unsigned)); // 8 MB
    int* gsrc       = (int*)alloc((size_t)nbins * SBINCAP * sizeof(int));          // 8 MB
    int* row_start  = (int*)alloc((size_t)N * sizeof(int));
    int* indeg      = (int*)alloc((size_t)N * sizeof(int));
    float* snorm    = (float*)alloc((size_t)N * sizeof(float));
    float* dnorm09  = (float*)alloc((size_t)N * sizeof(float));
    int* bincnt     = (int*)alloc((size_t)MAXBINS * sizeof(int));
    int* sbincnt    = (int*)alloc((size_t)MAXBINS * sizeof(int));
    int* colbase    = (int*)alloc((size_t)MAXBINS * sizeof(int));

    hipMemsetAsync(bincnt, 0, (size_t)MAXBINS * sizeof(int), stream);
    hipMemsetAsync(sbincnt, 0, (size_t)MAXBINS * sizeof(int), stream);

    const int gridB  = (E + CHB - 1) / CHB;      // 782
    const int total = N * NH;
    const int gridI = (total + HS + 255) / 256;  // covers sentinel row
    const int gridS = (total + 255) / 256;

    bin_kernel<<<gridB, 256, 0, stream>>>(src, dst, E, gpairs, bincnt,
                                          gsrc, sbincnt, nbins);
    binscan_kernel<<<1, 64, 0, stream>>>(bincnt, colbase, nbins, N);
    binB_kernel <<<nbins, 256, 0, stream>>>(gpairs, bincnt, colbase,
                                            row_start, indeg, dnorm09, col, N);
    binBs_kernel<<<nbins, 256, 0, stream>>>(gsrc, sbincnt, snorm, N);

    init_kernel<<<gridI, 256, 0, stream>>>((const float4*)features, snorm,
                                           H0, H1, F0h, N);

    for (int k = 0; k < KSTEPS; ++k) {
        const uint4* fin = (k & 1) ? (const uint4*)H1 : (const uint4*)H0;
        uint4*       fo  = (k & 1) ? H0 : H1;
        if (k == KSTEPS - 1) {
            step_kernel<1><<<gridS, 256, 0, stream>>>(
                fin, F0h, row_start, indeg, col, snorm, dnorm09,
                fo, (float4*)out, N);
        } else {
            step_kernel<0><<<gridS, 256, 0, stream>>>(
                fin, F0h, row_start, indeg, col, snorm, dnorm09,
                fo, nullptr, N);
        }
    }
}